// Round 1
// baseline (8489.731 us; speedup 1.0000x reference)
//
#include <hip/hip_runtime.h>
#include <cmath>

// GRU scan, 2 layers, B=64 T=4096 D=H=128.
// Design: 4 persistent WGs x 16 batch rows x 512 threads (8 waves).
//  - All recurrence weights live in VGPRs as stationary mfma_f32_16x16x32_bf16
//    B-fragments (wave u owns gate tiles u, u+8, u+16 => r,z,n for units 16u..16u+15).
//  - Hidden state: fp32 in registers (MFMA C-layout), bf16 copy in LDS for A-frags.
//  - Layer0 folds x-projection: A = [x_t | h0], K=256. n-gate keeps x/h parts in
//    separate accumulators (r multiplies only the h-part + b_hh).
//  - 2 __syncthreads per step; h1 LDS region double-buffered to drop the 3rd/4th.

#define Bsz  64
#define Tlen 4096
#define Din  128
#define Hd   128

typedef __attribute__((ext_vector_type(8))) short short8;   // 8 bf16 (4 VGPRs)
typedef __attribute__((ext_vector_type(4))) short short4v;  // 4 bf16
typedef __attribute__((ext_vector_type(4))) float float4v;  // MFMA acc / x vec

#define MFMA16(a, b, c) __builtin_amdgcn_mfma_f32_16x16x32_bf16((a), (b), (c), 0, 0, 0)

static __device__ __forceinline__ short f2bf(float f) {  // RTNE fp32->bf16 bits
  unsigned u = __builtin_bit_cast(unsigned, f);
  u = (u + 0x7FFFu + ((u >> 16) & 1u)) >> 16;
  return (short)u;
}

static __device__ __forceinline__ float sigm(float x) {
  return __builtin_amdgcn_rcpf(1.0f + __expf(-x));
}

static __device__ __forceinline__ float tanh_f(float x) {
  x = fmaxf(x, -30.0f);                 // avoid inf/inf NaN for very negative x
  float e = __expf(-2.0f * x);
  return (1.0f - e) * __builtin_amdgcn_rcpf(1.0f + e);
}

static __device__ __forceinline__ short8 loadw8(const float* __restrict__ p) {
  short8 r;
  #pragma unroll
  for (int j = 0; j < 8; ++j) r[j] = f2bf(p[j]);
  return r;
}

// LDS row layout (bf16): cols [0,128)=x_t  [128,256)=h0  [256,384)=h1 buf0
// [384,512)=h1 buf1, +8 pad shorts (row stride 1040B => 2-way max bank alias).
#define STRIDE 520

__global__ __launch_bounds__(512, 2) void gru_scan(
    const float* __restrict__ x,
    const float* __restrict__ Wih0, const float* __restrict__ Whh0,
    const float* __restrict__ bih0, const float* __restrict__ bhh0,
    const float* __restrict__ Wih1, const float* __restrict__ Whh1,
    const float* __restrict__ bih1, const float* __restrict__ bhh1,
    float* __restrict__ out) {
  __shared__ alignas(16) short Abuf[16 * STRIDE];

  const int tid   = threadIdx.x;
  const int wave  = tid >> 6;      // 0..7 : owns hidden units [16*wave, 16*wave+16)
  const int lane  = tid & 63;
  const int lc    = lane & 15;     // A: m | B: n | C: col
  const int quad  = lane >> 4;     // A/B: k-group | C: row-group
  const int q8    = quad * 8;
  const int bbase = blockIdx.x * 16;

  // ---- stationary weight fragments --------------------------------------
  // B-frag for tile n0, kstep s: lane holds W[n0+lc][32s + q8 + j], j=0..7
  const int nr = wave * 16 + lc;          // r-gate row in [3H]
  const int nz = 128 + wave * 16 + lc;    // z-gate row
  const int nn = 256 + wave * 16 + lc;    // n-gate row

  short8 fr0[8], fz0[8], fin0[4], fhn0[4];
  short8 fr1[8], fz1[8], fin1[4], fhn1[4];
  #pragma unroll
  for (int s = 0; s < 4; ++s) {
    const int k = 32 * s + q8;
    // layer0: A ksteps 0..3 = x (W_ih0), ksteps 4..7 = h0 (W_hh0)
    fr0[s]     = loadw8(Wih0 + nr * Din + k);
    fz0[s]     = loadw8(Wih0 + nz * Din + k);
    fin0[s]    = loadw8(Wih0 + nn * Din + k);
    fr0[s + 4] = loadw8(Whh0 + nr * Hd + k);
    fz0[s + 4] = loadw8(Whh0 + nz * Hd + k);
    fhn0[s]    = loadw8(Whh0 + nn * Hd + k);
    // layer1: A ksteps 0..3 = h0' (W_ih1), ksteps 4..7 = h1 (W_hh1)
    fr1[s]     = loadw8(Wih1 + nr * Hd + k);
    fz1[s]     = loadw8(Wih1 + nz * Hd + k);
    fin1[s]    = loadw8(Wih1 + nn * Hd + k);
    fr1[s + 4] = loadw8(Whh1 + nr * Hd + k);
    fz1[s + 4] = loadw8(Whh1 + nz * Hd + k);
    fhn1[s]    = loadw8(Whh1 + nn * Hd + k);
  }

  // combined biases per gate column (same for all 4 rows a lane owns)
  const float br0 = bih0[nr] + bhh0[nr];
  const float bz0 = bih0[nz] + bhh0[nz];
  const float bi0 = bih0[nn];
  const float bh0 = bhh0[nn];
  const float br1 = bih1[nr] + bhh1[nr];
  const float bz1 = bih1[nz] + bhh1[nz];
  const float bi1 = bih1[nn];
  const float bh1 = bhh1[nn];

  // ---- prologue: zero LDS, stage x_0 ------------------------------------
  for (int i = tid; i < 16 * STRIDE; i += 512) Abuf[i] = 0;
  __syncthreads();

  const int xrow = tid >> 5;        // 0..15 (batch row within WG)
  const int xd   = (tid & 31) * 4;  // 0..124
  const float* xbase = x + (size_t)(bbase + xrow) * Tlen * Din + xd;
  {
    const float4v xv = *(const float4v*)xbase;  // t = 0
    short4v s4;
    #pragma unroll
    for (int j = 0; j < 4; ++j) s4[j] = f2bf(xv[j]);
    *(short4v*)&Abuf[xrow * STRIDE + xd] = s4;
  }
  __syncthreads();

  // ---- the scan ----------------------------------------------------------
  float h0p[4] = {0.f, 0.f, 0.f, 0.f};
  float h1p[4] = {0.f, 0.f, 0.f, 0.f};
  const int aoff = lc * STRIDE + q8;  // A-frag base (row lc, k-group q8)

  #pragma unroll 2
  for (int t = 0; t < Tlen; ++t) {
    // prefetch x_{t+1} (consumed ~600+ cycles later, after barrier A)
    const int tn = (t + 1 < Tlen) ? t + 1 : t;
    const float4v xv = *(const float4v*)(xbase + (size_t)tn * Din);

    // ---- layer 0: [x_t | h0] @ [W_ih0 ; W_hh0]^T ----
    float4v ar = {0.f, 0.f, 0.f, 0.f}, az = {0.f, 0.f, 0.f, 0.f};
    float4v ain = {0.f, 0.f, 0.f, 0.f}, ahn = {0.f, 0.f, 0.f, 0.f};
    #pragma unroll
    for (int s = 0; s < 4; ++s) {
      const short8 a = *(const short8*)&Abuf[aoff + 32 * s];        // x part
      ar  = MFMA16(a, fr0[s], ar);
      az  = MFMA16(a, fz0[s], az);
      ain = MFMA16(a, fin0[s], ain);
    }
    #pragma unroll
    for (int s = 0; s < 4; ++s) {
      const short8 a = *(const short8*)&Abuf[aoff + 128 + 32 * s];  // h0 part
      ar  = MFMA16(a, fr0[s + 4], ar);
      az  = MFMA16(a, fz0[s + 4], az);
      ahn = MFMA16(a, fhn0[s], ahn);
    }
    __syncthreads();  // (A) all waves done reading x_t / h0 / h1[rb of t-1]

    float h0n[4];
    #pragma unroll
    for (int i = 0; i < 4; ++i) {
      const float r  = sigm(ar[i] + br0);
      const float z  = sigm(az[i] + bz0);
      const float nn_ = tanh_f(ain[i] + bi0 + r * (ahn[i] + bh0));
      h0n[i] = z * (h0p[i] - nn_) + nn_;
      h0p[i] = h0n[i];
    }
    #pragma unroll
    for (int i = 0; i < 4; ++i)
      Abuf[(quad * 4 + i) * STRIDE + 128 + wave * 16 + lc] = f2bf(h0n[i]);
    {
      short4v s4;
      #pragma unroll
      for (int j = 0; j < 4; ++j) s4[j] = f2bf(xv[j]);
      *(short4v*)&Abuf[xrow * STRIDE + xd] = s4;  // x_{t+1} over x_t
    }
    __syncthreads();  // (B) h0' and x_{t+1} visible

    // ---- layer 1: [h0' | h1] @ [W_ih1 ; W_hh1]^T ----
    const int rb = 256 + 128 * (t & 1);         // h1 read buffer
    const int wb = 256 + 128 * ((t & 1) ^ 1);   // h1 write buffer
    float4v cr = {0.f, 0.f, 0.f, 0.f}, cz = {0.f, 0.f, 0.f, 0.f};
    float4v cin = {0.f, 0.f, 0.f, 0.f}, chn = {0.f, 0.f, 0.f, 0.f};
    #pragma unroll
    for (int s = 0; s < 4; ++s) {
      const short8 a = *(const short8*)&Abuf[aoff + 128 + 32 * s];  // h0'
      cr  = MFMA16(a, fr1[s], cr);
      cz  = MFMA16(a, fz1[s], cz);
      cin = MFMA16(a, fin1[s], cin);
    }
    #pragma unroll
    for (int s = 0; s < 4; ++s) {
      const short8 a = *(const short8*)&Abuf[aoff + rb + 32 * s];   // h1
      cr  = MFMA16(a, fr1[s + 4], cr);
      cz  = MFMA16(a, fz1[s + 4], cz);
      chn = MFMA16(a, fhn1[s], chn);
    }
    #pragma unroll
    for (int i = 0; i < 4; ++i) {
      const float r  = sigm(cr[i] + br1);
      const float z  = sigm(cz[i] + bz1);
      const float nn_ = tanh_f(cin[i] + bi1 + r * (chn[i] + bh1));
      const float h  = z * (h1p[i] - nn_) + nn_;
      h1p[i] = h;
      Abuf[(quad * 4 + i) * STRIDE + wb + wave * 16 + lc] = f2bf(h);
    }
    // no barrier: writes go to the alternate h1 buffer; next step's barrier (A)
    // orders them against the next layer-1 reads, and barrier (A) also drains
    // this step's layer-1 reads before next step's h0'' write.
  }

  // ---- epilogue: final h from fp32 registers ----
  #pragma unroll
  for (int i = 0; i < 4; ++i) {
    const int b = bbase + quad * 4 + i;
    const int h = wave * 16 + lc;
    out[b * Hd + h]            = h0p[i];
    out[Bsz * Hd + b * Hd + h] = h1p[i];
  }
}

extern "C" void kernel_launch(void* const* d_in, const int* in_sizes, int n_in,
                              void* d_out, int out_size, void* d_ws, size_t ws_size,
                              hipStream_t stream) {
  (void)in_sizes; (void)n_in; (void)out_size; (void)d_ws; (void)ws_size;
  gru_scan<<<4, 512, 0, stream>>>(
      (const float*)d_in[0],
      (const float*)d_in[1], (const float*)d_in[2],
      (const float*)d_in[3], (const float*)d_in[4],
      (const float*)d_in[5], (const float*)d_in[6],
      (const float*)d_in[7], (const float*)d_in[8],
      (float*)d_out);
}